// Round 1
// 3298.901 us; speedup vs baseline: 1.8803x; 1.8803x over previous
//
#include <hip/hip_runtime.h>
#include <math.h>

#define NEGINF (-INFINITY)
#define NBOX 5625
#define NW 88          // 5632 bits = 88 u64 words
#define SORTN 8192

typedef __attribute__((ext_vector_type(8))) short short8;
typedef __attribute__((ext_vector_type(4))) float floatx4;

__device__ __forceinline__ unsigned short f2bf(float f) {
  unsigned u = __float_as_uint(f);
  u += 0x7fffu + ((u >> 16) & 1u);   // round-to-nearest-even
  return (unsigned short)(u >> 16);
}

__device__ __forceinline__ void gload16(const void* g, void* l) {
  __builtin_amdgcn_global_load_lds(
      (const __attribute__((address_space(1))) void*)g,
      (__attribute__((address_space(3))) void*)l, 16, 0, 0);
}

__device__ __forceinline__ unsigned long long shfl_u64(unsigned long long v, int lane) {
  int lo = __shfl((int)(unsigned)v, lane);
  int hi = __shfl((int)(unsigned)(v >> 32), lane);
  return ((unsigned long long)(unsigned)hi << 32) | (unsigned)lo;
}

// ---------------- conv 3x3 512->512 + bias + relu, output transposed [p][c] ----------------
__global__ __launch_bounds__(128) void conv3x3_relu(
    const float* __restrict__ feat, const float* __restrict__ w,
    const float* __restrict__ bias, float* __restrict__ xt) {
  const int ocg = blockIdx.x;      // 0..63 -> oc = ocg*8 .. +7
  const int pg  = blockIdx.y;      // 0..4  -> rows pg*5 .. pg*5+4
  const int t = threadIdx.x;
  const int lr = t / 25, lc = t % 25;
  const bool active = t < 125;
  const int h = pg * 5 + lr;
  __shared__ float sp[7][25];
  float acc[8];
#pragma unroll
  for (int o = 0; o < 8; o++) acc[o] = 0.f;
  const int r0 = pg * 5 - 1;
  for (int ic = 0; ic < 512; ++ic) {
    __syncthreads();
    for (int idx = t; idx < 175; idx += 128) {
      int rr = idx / 25, cc = idx % 25;
      int gr = r0 + rr;
      sp[rr][cc] = (gr >= 0 && gr < 25) ? feat[ic * 625 + gr * 25 + cc] : 0.f;
    }
    __syncthreads();
    if (active) {
      float v[9];
#pragma unroll
      for (int dy = 0; dy < 3; dy++) {
        v[dy * 3 + 0] = (lc > 0)  ? sp[lr + dy][lc - 1] : 0.f;
        v[dy * 3 + 1] = sp[lr + dy][lc];
        v[dy * 3 + 2] = (lc < 24) ? sp[lr + dy][lc + 1] : 0.f;
      }
      const float* wp = w + ((size_t)(ocg * 8) * 512 + ic) * 9;
#pragma unroll
      for (int o = 0; o < 8; o++) {
        const float* wo = wp + (size_t)o * 512 * 9;
        float s = acc[o];
#pragma unroll
        for (int k = 0; k < 9; k++) s = fmaf(v[k], wo[k], s);
        acc[o] = s;
      }
    }
  }
  if (active) {
    int p = h * 25 + lc;
#pragma unroll
    for (int o = 0; o < 8; o++) {
      int oc = ocg * 8 + o;
      xt[(size_t)p * 512 + oc] = fmaxf(acc[o] + bias[oc], 0.f);
    }
  }
}

// ---------------- 1x1 convs: cls (18) + reg (36), output [p][54] ----------------
__global__ void conv1x1_kernel(const float* __restrict__ xt,
    const float* __restrict__ cls_w, const float* __restrict__ cls_b,
    const float* __restrict__ reg_w, const float* __restrict__ reg_b,
    float* __restrict__ out) {
  int gid = blockIdx.x * blockDim.x + threadIdx.x;
  int p = gid >> 6, c = gid & 63;
  if (p >= 625 || c >= 54) return;
  const float* wrow;
  float b;
  if (c < 18) { wrow = cls_w + (size_t)c * 512; b = cls_b[c]; }
  else        { wrow = reg_w + (size_t)(c - 18) * 512; b = reg_b[c - 18]; }
  const float* xr = xt + (size_t)p * 512;
  float s = 0.f;
  for (int k = 0; k < 512; k++) s = fmaf(xr[k], wrow[k], s);
  out[p * 54 + c] = s + b;
}

// ---------------- softmax + anchors + decode + clip + min-size filter ----------------
__global__ void decode_kernel(const float* __restrict__ clsreg,
    const int* __restrict__ Hp, const int* __restrict__ Wp,
    float* __restrict__ boxes, float* __restrict__ areas, float* __restrict__ scores) {
  int n = blockIdx.x * blockDim.x + threadIdx.x;
  if (n >= NBOX) return;
  int p = n / 9, a = n % 9;
  int hh = p / 25, ww = p % 25;
  float Wlim = (float)(*Wp), Hlim = (float)(*Hp);
  float stride = (float)((*Wp) / 25);
  int ri = a / 3, si = a % 3;
  float ratio = (ri == 0) ? 0.5f : ((ri == 1) ? 1.0f : 2.0f);
  float size  = (si == 0) ? 128.f : ((si == 1) ? 256.f : 512.f);
  float hr = sqrtf(ratio);
  float wr = 1.0f / hr;
  float wsz = wr * size, hsz = hr * size;
  float bx1 = rintf(-wsz * 0.5f), by1 = rintf(-hsz * 0.5f);
  float bx2 = rintf( wsz * 0.5f), by2 = rintf( hsz * 0.5f);
  float sx = (float)ww * stride, sy = (float)hh * stride;
  float a0 = sx + bx1, a1 = sy + by1, a2 = sx + bx2, a3 = sy + by2;
  float ax = (a0 + a2) * 0.5f, ay = (a1 + a3) * 0.5f;
  float aw = fmaxf(a2 - a0, 1e-6f), ah = fmaxf(a3 - a1, 1e-6f);
  const float* row = clsreg + p * 54;
  float c0 = row[a * 2], c1 = row[a * 2 + 1];
  float m = fmaxf(c0, c1);
  float e0 = expf(c0 - m), e1 = expf(c1 - m);
  float prob = e1 / (e0 + e1);
  float tx = row[18 + a * 4 + 0], ty = row[18 + a * 4 + 1];
  float tw = row[18 + a * 4 + 2], th = row[18 + a * 4 + 3];
  float px = tx * aw + ax, py = ty * ah + ay;
  float pw = aw * fminf(expf(tw), 1e6f);
  float ph = ah * fminf(expf(th), 1e6f);
  float x1 = px - 0.5f * pw, y1 = py - 0.5f * ph;
  float x2 = px + 0.5f * pw, y2 = py + 0.5f * ph;
  x1 = fminf(fmaxf(x1, 0.f), Wlim - 1.f); x2 = fminf(fmaxf(x2, 0.f), Wlim - 1.f);
  y1 = fminf(fmaxf(y1, 0.f), Hlim - 1.f); y2 = fminf(fmaxf(y2, 0.f), Hlim - 1.f);
  float bw = fmaxf(x2 - x1, 0.f), bh = fmaxf(y2 - y1, 0.f);
  bool ok = (bw >= 1.0f) && (bh >= 1.0f);
  boxes[n * 4 + 0] = x1; boxes[n * 4 + 1] = y1;
  boxes[n * 4 + 2] = x2; boxes[n * 4 + 3] = y2;
  areas[n] = (x2 - x1) * (y2 - y1);
  scores[n] = ok ? prob : NEGINF;
}

// ---------------- NMS stage 1: pack sortable keys ----------------
// key = ~( (order-preserving score bits)<<32 | (~idx) )  -> ascending sort gives
// descending score, ascending original index on ties (matches jnp.argmax).
__global__ __launch_bounds__(256) void nms_pack(const float* __restrict__ scores,
    unsigned long long* __restrict__ keys) {
  int n = blockIdx.x * 256 + threadIdx.x;
  if (n >= SORTN) return;
  unsigned long long key;
  if (n < NBOX) {
    unsigned u = __float_as_uint(scores[n]);
    u = (u & 0x80000000u) ? ~u : (u | 0x80000000u);
    key = ~(((unsigned long long)u << 32) | (unsigned long long)(0xFFFFFFFFu ^ (unsigned)n));
  } else {
    key = ~0ULL;   // pad: sorts last
  }
  keys[n] = key;
}

// ---------------- NMS stage 2: bitonic sort 8192 u64 keys, one block ----------------
__global__ __launch_bounds__(1024) void nms_sort(unsigned long long* __restrict__ keys) {
  __shared__ unsigned long long s[SORTN];   // 64 KB
  const int t = threadIdx.x;
  for (int i = t; i < SORTN; i += 1024) s[i] = keys[i];
  __syncthreads();
  for (int k = 2; k <= SORTN; k <<= 1) {
    for (int j = k >> 1; j > 0; j >>= 1) {
      for (int i = t; i < SORTN; i += 1024) {
        int l = i ^ j;
        if (l > i) {
          unsigned long long a = s[i], b = s[l];
          bool up = ((i & k) == 0);
          if ((a > b) == up) { s[i] = b; s[l] = a; }
        }
      }
      __syncthreads();
    }
  }
  for (int i = t; i < SORTN; i += 1024) keys[i] = s[i];
}

// ---------------- NMS stage 3: unpack sorted order -> gathered boxes + valid bitmask ----
__global__ __launch_bounds__(64) void nms_unpack(
    const unsigned long long* __restrict__ keys,
    const float* __restrict__ boxes, const float* __restrict__ areas,
    float* __restrict__ sbox, float* __restrict__ sarea,
    unsigned long long* __restrict__ vmask) {
  int i = blockIdx.x * 64 + threadIdx.x;   // i < 5632
  unsigned long long k = ~keys[i];
  unsigned up = (unsigned)(k >> 32);
  bool valid = up > 0x007FFFFFu;           // score > -inf (and not padding)
  if (valid) {
    unsigned n = 0xFFFFFFFFu ^ (unsigned)k;
    sbox[i * 4 + 0] = boxes[n * 4 + 0];
    sbox[i * 4 + 1] = boxes[n * 4 + 1];
    sbox[i * 4 + 2] = boxes[n * 4 + 2];
    sbox[i * 4 + 3] = boxes[n * 4 + 3];
    sarea[i] = areas[n];
  } else {
    sbox[i * 4 + 0] = 0.f; sbox[i * 4 + 1] = 0.f;
    sbox[i * 4 + 2] = 0.f; sbox[i * 4 + 3] = 0.f;
    sarea[i] = 0.f;
  }
  unsigned long long vb = __ballot(valid);
  if (threadIdx.x == 0) vmask[blockIdx.x] = vb;
}

// ---------------- NMS stage 4: pairwise IoU suppression bitmask ----------------
// mask[r][cb] bit c set  <=>  j = cb*64+c > r  and  IoU(r,j) > 0.7
__global__ __launch_bounds__(64) void nms_mask(
    const float* __restrict__ sbox, const float* __restrict__ sarea,
    unsigned long long* __restrict__ mask) {
  const int cb = blockIdx.x, rb = blockIdx.y;
  const int t = threadIdx.x;
  const int r = rb * 64 + t;
  if (cb < rb) { mask[(size_t)r * NW + cb] = 0ULL; return; }
  __shared__ float cx1[64], cy1[64], cx2[64], cy2[64], car[64];
  int j = cb * 64 + t;
  cx1[t] = sbox[j * 4 + 0]; cy1[t] = sbox[j * 4 + 1];
  cx2[t] = sbox[j * 4 + 2]; cy2[t] = sbox[j * 4 + 3];
  car[t] = sarea[j];
  __syncthreads();
  float rx1 = sbox[r * 4 + 0], ry1 = sbox[r * 4 + 1];
  float rx2 = sbox[r * 4 + 2], ry2 = sbox[r * 4 + 3];
  float rar = sarea[r];
  unsigned long long m = 0;
  int c0 = (cb == rb) ? (t + 1) : 0;
  for (int c = c0; c < 64; ++c) {
    float iw = fmaxf(fminf(rx2, cx2[c]) - fmaxf(rx1, cx1[c]), 0.f);
    float ih = fmaxf(fminf(ry2, cy2[c]) - fmaxf(ry1, cy1[c]), 0.f);
    float inter = iw * ih;
    float iou = inter / fmaxf(rar + car[c] - inter, 1e-12f);
    if (iou > 0.7f) m |= (1ULL << c);
  }
  mask[(size_t)r * NW + cb] = m;
}

// ---------------- NMS stage 5: serial bitmask scan, one wave, no barriers ----------------
__global__ __launch_bounds__(64) void nms_scan(
    const unsigned long long* __restrict__ vmask,
    const unsigned long long* __restrict__ mask,
    const float* __restrict__ sbox, float* __restrict__ dout) {
  float* props  = dout;
  float* validf = dout + 4000;
  const int l = threadIdx.x;
  // lane l owns removed/valid words l (rem0) and 64+l for l<24 (rem1)
  unsigned long long rem0 = 0, rem1 = 0;
  unsigned long long v0 = vmask[l];
  unsigned long long v1 = (l < 24) ? vmask[64 + l] : 0ULL;
  int kept = 0;
  for (int w = 0; w < NW; ++w) {
    int owner = (w < 64) ? w : (w - 64);
    for (;;) {
      unsigned long long myc = (w < 64) ? (v0 & ~rem0) : (v1 & ~rem1);
      unsigned long long cand = shfl_u64(myc, owner);
      if (!cand) break;
      int b = __ffsll((unsigned long long)cand) - 1;
      int i = w * 64 + b;
      if (l < 4) props[kept * 4 + l] = sbox[(size_t)i * 4 + l];
      if (l == 0) validf[kept] = 1.0f;
      kept++;
      if (kept == 1000) { w = NW; break; }
      unsigned long long m0 = mask[(size_t)i * NW + l];
      unsigned long long m1 = (l < 24) ? mask[(size_t)i * NW + 64 + l] : 0ULL;
      rem0 |= m0; rem1 |= m1;
      if (w < 64) { if (l == w) rem0 |= (1ULL << b); }
      else        { if (l == w - 64) rem1 |= (1ULL << b); }
    }
  }
  for (int z = kept * 4 + l; z < 4000; z += 64) props[z] = 0.f;
  for (int z = kept + l; z < 1000; z += 64) validf[z] = 0.f;
}

// ---------------- ROI max-pool -> bf16 feats [1024][25088], pad rows zeroed ----------------
__global__ __launch_bounds__(256) void roipool_kernel(
    const float* __restrict__ feat, const float* __restrict__ dout,
    const int* __restrict__ Wp, unsigned short* __restrict__ feats) {
  const int r = blockIdx.x;
  const int t = threadIdx.x;
  const float* props  = dout;
  const float* validf = dout + 4000;
  unsigned short* outr = feats + (size_t)r * 25088;
  bool dead = (r >= 1000) || (validf[r] == 0.0f);
  if (dead) {
    for (int i = t; i < 25088; i += 256) outr[i] = 0;
    return;
  }
  const float scale = 1.0f / (float)((*Wp) / 25);
  __shared__ int hs_[7], he_[7], ws_[7], we_[7];
  if (t < 7) {
    float fx1 = props[r * 4 + 0], fy1 = props[r * 4 + 1];
    float fx2 = props[r * 4 + 2], fy2 = props[r * 4 + 3];
    int x1 = (int)rintf(fx1 * scale), y1 = (int)rintf(fy1 * scale);
    int x2 = (int)rintf(fx2 * scale), y2 = (int)rintf(fy2 * scale);
    float roiw = (float)max(x2 - x1 + 1, 1);
    float roih = (float)max(y2 - y1 + 1, 1);
    float bw = roiw / 7.0f, bh = roih / 7.0f;
    float jf = (float)t;
    int w0 = (int)floorf(jf * bw) + x1;
    int w1 = (int)ceilf((jf + 1.f) * bw) + x1;
    int h0 = (int)floorf(jf * bh) + y1;
    int h1 = (int)ceilf((jf + 1.f) * bh) + y1;
    ws_[t] = min(max(w0, 0), 25); we_[t] = min(max(w1, 0), 25);
    hs_[t] = min(max(h0, 0), 25); he_[t] = min(max(h1, 0), 25);
  }
  __syncthreads();
  for (int idx = t; idx < 25088; idx += 256) {
    int c = idx / 49;
    int ij = idx % 49;
    int i = ij / 7, j = ij % 7;
    int h0 = hs_[i], h1 = min(he_[i], h0 + 6);
    int w0 = ws_[j], w1 = min(we_[j], w0 + 6);
    float m = NEGINF;
    const float* fp = feat + (size_t)c * 625;
    for (int y = h0; y < h1; y++)
      for (int x = w0; x < w1; x++)
        m = fmaxf(m, fp[y * 25 + x]);
    outr[idx] = (h0 < h1 && w0 < w1) ? f2bf(m) : 0;
  }
}

// ---------------- bf16 MFMA GEMM: C[128m x 128n] (f32) = A[M,K]bf16 * B[N,K]^T bf16 ----------
// m97 structure: BK=32, 4 waves, 4x4 16x16x32 tiles/wave, global_load_lds width 16.
__global__ __launch_bounds__(256) void gemm_bt_bf16(
    const unsigned short* __restrict__ A, int lda,
    const unsigned short* __restrict__ B, int ldb,
    const float* __restrict__ bias, float* __restrict__ C, int ldc,
    int K, int beta) {
  __shared__ unsigned short As[128 * 32];
  __shared__ unsigned short Bs[128 * 32];
  const int t = threadIdx.x;
  const int lane = t & 63;
  const int wv = t >> 6;
  const int wr = wv >> 1, wc = wv & 1;
  const int quad = lane >> 4, l16 = lane & 15;
  const int m0 = blockIdx.x * 128, n0 = blockIdx.y * 128;
  floatx4 acc[4][4];
#pragma unroll
  for (int mi = 0; mi < 4; mi++)
#pragma unroll
    for (int ni = 0; ni < 4; ni++) acc[mi][ni] = (floatx4){0.f, 0.f, 0.f, 0.f};
  const int srow = t >> 2;
  const int scol = (t & 3) * 8;
  const unsigned short* Ag0 = A + (size_t)(m0 + srow) * lda + scol;
  const unsigned short* Ag1 = A + (size_t)(m0 + 64 + srow) * lda + scol;
  const unsigned short* Bg0 = B + (size_t)(n0 + srow) * ldb + scol;
  const unsigned short* Bg1 = B + (size_t)(n0 + 64 + srow) * ldb + scol;
  unsigned short* la0 = As + t * 8;
  unsigned short* la1 = As + 2048 + t * 8;
  unsigned short* lb0 = Bs + t * 8;
  unsigned short* lb1 = Bs + 2048 + t * 8;
  for (int kt = 0; kt < K; kt += 32) {
    __syncthreads();
    gload16(Ag0 + kt, la0);
    gload16(Ag1 + kt, la1);
    gload16(Bg0 + kt, lb0);
    gload16(Bg1 + kt, lb1);
    __syncthreads();
    short8 af[4], bfr[4];
#pragma unroll
    for (int mi = 0; mi < 4; mi++)
      af[mi] = *(const short8*)(As + (wr * 64 + mi * 16 + l16) * 32 + quad * 8);
#pragma unroll
    for (int ni = 0; ni < 4; ni++)
      bfr[ni] = *(const short8*)(Bs + (wc * 64 + ni * 16 + l16) * 32 + quad * 8);
#pragma unroll
    for (int mi = 0; mi < 4; mi++)
#pragma unroll
      for (int ni = 0; ni < 4; ni++)
        acc[mi][ni] = __builtin_amdgcn_mfma_f32_16x16x32_bf16(af[mi], bfr[ni], acc[mi][ni], 0, 0, 0);
  }
#pragma unroll
  for (int mi = 0; mi < 4; mi++) {
#pragma unroll
    for (int ni = 0; ni < 4; ni++) {
      int gn = n0 + wc * 64 + ni * 16 + l16;
      float bv = bias ? bias[gn] : 0.f;
#pragma unroll
      for (int r = 0; r < 4; r++) {
        int gm = m0 + wr * 64 + mi * 16 + quad * 4 + r;
        size_t o = (size_t)gm * ldc + gn;
        float v = acc[mi][ni][r] + bv;
        C[o] = beta ? (C[o] + v) : v;
      }
    }
  }
}

// ---------------- weight / activation conversion kernels ----------------
// fc1 K-chunk: o[n][k] = bf16(w[n][koff+k]), n<4096, k<6272
__global__ __launch_bounds__(256) void cvt_fc1_chunk(
    const float* __restrict__ w, unsigned short* __restrict__ o, int koff) {
  int idx = blockIdx.x * 256 + threadIdx.x;
  int e = idx * 4;
  if (e >= 4096 * 6272) return;
  int n = e / 6272, k = e - n * 6272;
  float4 v = *(const float4*)(w + (size_t)n * 25088 + koff + k);
  ushort4 r = make_ushort4(f2bf(v.x), f2bf(v.y), f2bf(v.z), f2bf(v.w));
  *(ushort4*)(o + e) = r;
}

__global__ __launch_bounds__(256) void cvt_f32_bf16(
    const float* __restrict__ in, unsigned short* __restrict__ out, int n4) {
  int idx = blockIdx.x * 256 + threadIdx.x;
  if (idx >= n4) return;
  float4 v = *(const float4*)(in + (size_t)idx * 4);
  ushort4 r = make_ushort4(f2bf(v.x), f2bf(v.y), f2bf(v.z), f2bf(v.w));
  *(ushort4*)(out + (size_t)idx * 4) = r;
}

// h1bf = bf16(h1f + fc1_b[col]), 1024x4096
__global__ __launch_bounds__(256) void cvt_h1(
    const float* __restrict__ h1, const float* __restrict__ b,
    unsigned short* __restrict__ o) {
  int idx = blockIdx.x * 256 + threadIdx.x;
  int e = idx * 4;
  if (e >= 1024 * 4096) return;
  int col = e & 4095;
  float4 v = *(const float4*)(h1 + e);
  float4 bb = *(const float4*)(b + col);
  ushort4 r = make_ushort4(f2bf(v.x + bb.x), f2bf(v.y + bb.y),
                           f2bf(v.z + bb.z), f2bf(v.w + bb.w));
  *(ushort4*)(o + e) = r;
}

// ---------------- final fc: logits (21) + deltas (4), f32 ----------------
__global__ __launch_bounds__(256) void final_fc(
    const float* __restrict__ h2, const float* __restrict__ cw,
    const float* __restrict__ cb, const float* __restrict__ bw,
    const float* __restrict__ bb, float* __restrict__ logits,
    float* __restrict__ deltas) {
  int r = blockIdx.x;
  const float* x = h2 + (size_t)r * 4096;
  int lane = threadIdx.x & 63, w = threadIdx.x >> 6;
  for (int o = w; o < 25; o += 4) {
    const float* wt = (o < 21) ? (cw + (size_t)o * 4096) : (bw + (size_t)(o - 21) * 4096);
    float s = 0.f;
    for (int k = lane; k < 4096; k += 64) s = fmaf(x[k], wt[k], s);
#pragma unroll
    for (int off = 32; off >= 1; off >>= 1) s += __shfl_xor(s, off);
    if (lane == 0) {
      if (o < 21) logits[r * 21 + o] = s + cb[o];
      else        deltas[r * 4 + (o - 21)] = s + bb[o - 21];
    }
  }
}

extern "C" void kernel_launch(void* const* d_in, const int* in_sizes, int n_in,
                              void* d_out, int out_size, void* d_ws, size_t ws_size,
                              hipStream_t stream) {
  const float* features    = (const float*)d_in[0];
  const float* conv_w      = (const float*)d_in[1];
  const float* conv_b      = (const float*)d_in[2];
  const float* cls_w       = (const float*)d_in[3];
  const float* cls_b       = (const float*)d_in[4];
  const float* reg_w       = (const float*)d_in[5];
  const float* reg_b       = (const float*)d_in[6];
  const float* fc1_w       = (const float*)d_in[7];
  const float* fc1_b       = (const float*)d_in[8];
  const float* fc2_w       = (const float*)d_in[9];
  const float* fc2_b       = (const float*)d_in[10];
  const float* cls_score_w = (const float*)d_in[11];
  const float* cls_score_b = (const float*)d_in[12];
  const float* bbox_w      = (const float*)d_in[13];
  const float* bbox_b      = (const float*)d_in[14];
  const int*   Hp          = (const int*)d_in[15];
  const int*   Wp          = (const int*)d_in[16];
  float* out = (float*)d_out;

  // ---- workspace layout (bytes), peak = 121.1 MB ----
  char* w8 = (char*)d_ws;
  float* xt     = (float*)w8;                    // 1,280,000
  float* clsreg = xt + 320000;                   //   135,000
  float* boxes  = clsreg + 33750;                //    90,000
  float* areas  = boxes + 22500;                 //    22,500
  float* scores = areas + 5625;                  //    22,500  -> small end @1,550,000
  unsigned short* feats = (unsigned short*)(w8 + 1550000);    // 1024*25088*2 = 51,380,224
  float* h1f            = (float*)(w8 + 52930224);            // 1024*4096*4  = 16,777,216
  unsigned short* wchunk = (unsigned short*)(w8 + 69707440);  // 4096*6272*2  = 51,380,224 -> end 121,087,664
  // overlays (regions dead by the time they're used):
  unsigned short* fc2wb = wchunk;                              // 33,554,432 (after fc1 done)
  unsigned short* h1b   = (unsigned short*)(w8 + 69707440 + 33554432); // 8,388,608
  float* h2             = (float*)feats;                       // 16,777,216 (feats dead after fc1)
  // NMS scratch overlays the feats region (dead until roipool writes it):
  char* nbase = w8 + 1550000;
  unsigned long long* keys  = (unsigned long long*)nbase;            //    65,536
  float* sbox               = (float*)(nbase + 65536);               //    90,112
  float* sarea              = (float*)(nbase + 155648);              //    22,528
  unsigned long long* vmask = (unsigned long long*)(nbase + 178176); //       704
  unsigned long long* mask  = (unsigned long long*)(nbase + 178880); // 3,965,056 -> end 4,143,936 (< 51 MB)

  conv3x3_relu<<<dim3(64, 5), 128, 0, stream>>>(features, conv_w, conv_b, xt);
  conv1x1_kernel<<<dim3(157), 256, 0, stream>>>(xt, cls_w, cls_b, reg_w, reg_b, clsreg);
  decode_kernel<<<dim3(23), 256, 0, stream>>>(clsreg, Hp, Wp, boxes, areas, scores);

  // ---- NMS: sort + pairwise mask + one-wave bitmask scan (== greedy NMS) ----
  nms_pack<<<dim3(SORTN / 256), 256, 0, stream>>>(scores, keys);
  nms_sort<<<dim3(1), 1024, 0, stream>>>(keys);
  nms_unpack<<<dim3(NW), 64, 0, stream>>>(keys, boxes, areas, sbox, sarea, vmask);
  nms_mask<<<dim3(NW, NW), 64, 0, stream>>>(sbox, sarea, mask);
  nms_scan<<<dim3(1), 64, 0, stream>>>(vmask, mask, sbox, out);

  roipool_kernel<<<dim3(1024), 256, 0, stream>>>(features, out, Wp, feats);

  // fc1: (1024,25088)bf16 x (4096,25088)^T in 4 K-chunks of 6272, accumulate f32
  for (int kc = 0; kc < 4; kc++) {
    cvt_fc1_chunk<<<dim3(25088), 256, 0, stream>>>(fc1_w, wchunk, kc * 6272);
    gemm_bt_bf16<<<dim3(8, 32), 256, 0, stream>>>(
        feats + kc * 6272, 25088, wchunk, 6272, nullptr, h1f, 4096, 6272, kc > 0 ? 1 : 0);
  }
  cvt_h1<<<dim3(4096), 256, 0, stream>>>(h1f, fc1_b, h1b);

  // fc2: (1024,4096) x (4096,4096)^T + bias -> h2 f32
  cvt_f32_bf16<<<dim3(16384), 256, 0, stream>>>(fc2_w, fc2wb, 4194304);
  gemm_bt_bf16<<<dim3(8, 32), 256, 0, stream>>>(
      h1b, 4096, fc2wb, 4096, fc2_b, h2, 4096, 4096, 0);

  // logits + deltas
  final_fc<<<dim3(1000), 256, 0, stream>>>(h2, cls_score_w, cls_score_b,
                                           bbox_w, bbox_b, out + 5000, out + 26000);
}

// Round 3
// 3178.546 us; speedup vs baseline: 1.9515x; 1.0379x over previous
//
#include <hip/hip_runtime.h>
#include <math.h>

#define NEGINF (-INFINITY)
#define NBOX 5625
#define NW 88          // 5632 bits = 88 u64 words
#define SORTN 8192

typedef __attribute__((ext_vector_type(8))) short short8;
typedef __attribute__((ext_vector_type(4))) float floatx4;

__device__ __forceinline__ unsigned short f2bf(float f) {
  unsigned u = __float_as_uint(f);
  u += 0x7fffu + ((u >> 16) & 1u);   // round-to-nearest-even
  return (unsigned short)(u >> 16);
}

__device__ __forceinline__ void gload16(const void* g, void* l) {
  __builtin_amdgcn_global_load_lds(
      (const __attribute__((address_space(1))) void*)g,
      (__attribute__((address_space(3))) void*)l, 16, 0, 0);
}

__device__ __forceinline__ unsigned long long shfl_u64(unsigned long long v, int lane) {
  int lo = __shfl((int)(unsigned)v, lane);
  int hi = __shfl((int)(unsigned)(v >> 32), lane);
  return ((unsigned long long)(unsigned)hi << 32) | (unsigned)lo;
}

// ---------------- weight transpose: w[oc][ic][9] -> wt[ic][oc*9+k] ----------------
__global__ __launch_bounds__(256) void wtrans_kernel(
    const float* __restrict__ w, float* __restrict__ wt) {
  int e = blockIdx.x * 256 + threadIdx.x;
  if (e >= 512 * 512 * 9) return;
  int oc = e / 4608;
  int rem = e - oc * 4608;
  int ic = rem / 9;
  int k = rem - ic * 9;
  wt[(size_t)ic * 4608 + oc * 9 + k] = w[e];
}

// ---------------- conv 3x3 512->512 + bias + relu, BIT-IDENTICAL fmaf chain ----------------
// Per (pixel, oc): acc starts 0, ic = 0..511 ascending, k = 0..8 ascending fmaf —
// exactly the round-1 passing kernel's arithmetic. Only the load strategy differs:
// 2 ocs/thread, grid (256,5) = 1280 blocks (10 waves/CU), weights via 9 pipelined
// dwordx2 vector loads from the transposed layout, features loaded directly (no LDS,
// no barriers).
__global__ __launch_bounds__(128) void conv3x3_o2(
    const float* __restrict__ feat, const float* __restrict__ wt,
    const float* __restrict__ bias, float* __restrict__ xt) {
  const int og = blockIdx.x;       // 0..255 -> oc = og*2, og*2+1
  const int pg = blockIdx.y;       // 0..4   -> rows pg*5 .. +4
  const int t = threadIdx.x;
  if (t >= 125) return;
  const int lr = t / 25, lc = t % 25;
  const int h = pg * 5 + lr;
  const bool ok_t = (h > 0), ok_b = (h < 24);
  const bool ok_l = (lc > 0), ok_r = (lc < 24);
  const float* fbase = feat + h * 25 + lc;
  int vz;
  asm volatile("v_mov_b32 %0, 0" : "=v"(vz));   // opaque 0: force VGPR addressing
  const float* wbase = wt + og * 18 + vz;
  float acc0 = 0.f, acc1 = 0.f;
#pragma unroll 2
  for (int ic = 0; ic < 512; ++ic) {
    const float* fp = fbase + (size_t)ic * 625;
    float v[9];
    v[0] = (ok_t && ok_l) ? fp[-26] : 0.f;
    v[1] = ok_t ? fp[-25] : 0.f;
    v[2] = (ok_t && ok_r) ? fp[-24] : 0.f;
    v[3] = ok_l ? fp[-1] : 0.f;
    v[4] = fp[0];
    v[5] = ok_r ? fp[1] : 0.f;
    v[6] = (ok_b && ok_l) ? fp[24] : 0.f;
    v[7] = ok_b ? fp[25] : 0.f;
    v[8] = (ok_b && ok_r) ? fp[26] : 0.f;
    float wq[18];
    const float2* wp2 = (const float2*)(wbase + (size_t)ic * 4608);
#pragma unroll
    for (int q = 0; q < 9; q++) *(float2*)(&wq[q * 2]) = wp2[q];
    float s0 = acc0, s1 = acc1;
#pragma unroll
    for (int k = 0; k < 9; k++) s0 = fmaf(v[k], wq[k], s0);
#pragma unroll
    for (int k = 0; k < 9; k++) s1 = fmaf(v[k], wq[9 + k], s1);
    acc0 = s0; acc1 = s1;
  }
  const int p = h * 25 + lc;
  const int oc0 = og * 2;
  xt[(size_t)p * 512 + oc0]     = fmaxf(acc0 + bias[oc0], 0.f);
  xt[(size_t)p * 512 + oc0 + 1] = fmaxf(acc1 + bias[oc0 + 1], 0.f);
}

// ---------------- 1x1 convs: cls (18) + reg (36), output [p][54] ----------------
__global__ void conv1x1_kernel(const float* __restrict__ xt,
    const float* __restrict__ cls_w, const float* __restrict__ cls_b,
    const float* __restrict__ reg_w, const float* __restrict__ reg_b,
    float* __restrict__ out) {
  int gid = blockIdx.x * blockDim.x + threadIdx.x;
  int p = gid >> 6, c = gid & 63;
  if (p >= 625 || c >= 54) return;
  const float* wrow;
  float b;
  if (c < 18) { wrow = cls_w + (size_t)c * 512; b = cls_b[c]; }
  else        { wrow = reg_w + (size_t)(c - 18) * 512; b = reg_b[c - 18]; }
  const float* xr = xt + (size_t)p * 512;
  float s = 0.f;
  for (int k = 0; k < 512; k++) s = fmaf(xr[k], wrow[k], s);
  out[p * 54 + c] = s + b;
}

// ---------------- softmax + anchors + decode + clip + min-size filter ----------------
__global__ void decode_kernel(const float* __restrict__ clsreg,
    const int* __restrict__ Hp, const int* __restrict__ Wp,
    float* __restrict__ boxes, float* __restrict__ areas, float* __restrict__ scores) {
  int n = blockIdx.x * blockDim.x + threadIdx.x;
  if (n >= NBOX) return;
  int p = n / 9, a = n % 9;
  int hh = p / 25, ww = p % 25;
  float Wlim = (float)(*Wp), Hlim = (float)(*Hp);
  float stride = (float)((*Wp) / 25);
  int ri = a / 3, si = a % 3;
  float ratio = (ri == 0) ? 0.5f : ((ri == 1) ? 1.0f : 2.0f);
  float size  = (si == 0) ? 128.f : ((si == 1) ? 256.f : 512.f);
  float hr = sqrtf(ratio);
  float wr = 1.0f / hr;
  float wsz = wr * size, hsz = hr * size;
  float bx1 = rintf(-wsz * 0.5f), by1 = rintf(-hsz * 0.5f);
  float bx2 = rintf( wsz * 0.5f), by2 = rintf( hsz * 0.5f);
  float sx = (float)ww * stride, sy = (float)hh * stride;
  float a0 = sx + bx1, a1 = sy + by1, a2 = sx + bx2, a3 = sy + by2;
  float ax = (a0 + a2) * 0.5f, ay = (a1 + a3) * 0.5f;
  float aw = fmaxf(a2 - a0, 1e-6f), ah = fmaxf(a3 - a1, 1e-6f);
  const float* row = clsreg + p * 54;
  float c0 = row[a * 2], c1 = row[a * 2 + 1];
  float m = fmaxf(c0, c1);
  float e0 = expf(c0 - m), e1 = expf(c1 - m);
  float prob = e1 / (e0 + e1);
  float tx = row[18 + a * 4 + 0], ty = row[18 + a * 4 + 1];
  float tw = row[18 + a * 4 + 2], th = row[18 + a * 4 + 3];
  float px = tx * aw + ax, py = ty * ah + ay;
  float pw = aw * fminf(expf(tw), 1e6f);
  float ph = ah * fminf(expf(th), 1e6f);
  float x1 = px - 0.5f * pw, y1 = py - 0.5f * ph;
  float x2 = px + 0.5f * pw, y2 = py + 0.5f * ph;
  x1 = fminf(fmaxf(x1, 0.f), Wlim - 1.f); x2 = fminf(fmaxf(x2, 0.f), Wlim - 1.f);
  y1 = fminf(fmaxf(y1, 0.f), Hlim - 1.f); y2 = fminf(fmaxf(y2, 0.f), Hlim - 1.f);
  float bw = fmaxf(x2 - x1, 0.f), bh = fmaxf(y2 - y1, 0.f);
  bool ok = (bw >= 1.0f) && (bh >= 1.0f);
  boxes[n * 4 + 0] = x1; boxes[n * 4 + 1] = y1;
  boxes[n * 4 + 2] = x2; boxes[n * 4 + 3] = y2;
  areas[n] = (x2 - x1) * (y2 - y1);
  scores[n] = ok ? prob : NEGINF;
}

// ---------------- NMS stage 1: pack sortable keys ----------------
__global__ __launch_bounds__(256) void nms_pack(const float* __restrict__ scores,
    unsigned long long* __restrict__ keys) {
  int n = blockIdx.x * 256 + threadIdx.x;
  if (n >= SORTN) return;
  unsigned long long key;
  if (n < NBOX) {
    unsigned u = __float_as_uint(scores[n]);
    u = (u & 0x80000000u) ? ~u : (u | 0x80000000u);
    key = ~(((unsigned long long)u << 32) | (unsigned long long)(0xFFFFFFFFu ^ (unsigned)n));
  } else {
    key = ~0ULL;   // pad: sorts last
  }
  keys[n] = key;
}

// ---------------- NMS stage 2: bitonic sort 8192 u64 keys, one block ----------------
__global__ __launch_bounds__(1024) void nms_sort(unsigned long long* __restrict__ keys) {
  __shared__ unsigned long long s[SORTN];   // 64 KB
  const int t = threadIdx.x;
  for (int i = t; i < SORTN; i += 1024) s[i] = keys[i];
  __syncthreads();
  for (int k = 2; k <= SORTN; k <<= 1) {
    for (int j = k >> 1; j > 0; j >>= 1) {
      for (int i = t; i < SORTN; i += 1024) {
        int l = i ^ j;
        if (l > i) {
          unsigned long long a = s[i], b = s[l];
          bool up = ((i & k) == 0);
          if ((a > b) == up) { s[i] = b; s[l] = a; }
        }
      }
      __syncthreads();
    }
  }
  for (int i = t; i < SORTN; i += 1024) keys[i] = s[i];
}

// ---------------- NMS stage 3: unpack sorted order ----------------
__global__ __launch_bounds__(64) void nms_unpack(
    const unsigned long long* __restrict__ keys,
    const float* __restrict__ boxes, const float* __restrict__ areas,
    float* __restrict__ sbox, float* __restrict__ sarea,
    unsigned long long* __restrict__ vmask) {
  int i = blockIdx.x * 64 + threadIdx.x;   // i < 5632
  unsigned long long k = ~keys[i];
  unsigned up = (unsigned)(k >> 32);
  bool valid = up > 0x007FFFFFu;           // score > -inf (and not padding)
  if (valid) {
    unsigned n = 0xFFFFFFFFu ^ (unsigned)k;
    sbox[i * 4 + 0] = boxes[n * 4 + 0];
    sbox[i * 4 + 1] = boxes[n * 4 + 1];
    sbox[i * 4 + 2] = boxes[n * 4 + 2];
    sbox[i * 4 + 3] = boxes[n * 4 + 3];
    sarea[i] = areas[n];
  } else {
    sbox[i * 4 + 0] = 0.f; sbox[i * 4 + 1] = 0.f;
    sbox[i * 4 + 2] = 0.f; sbox[i * 4 + 3] = 0.f;
    sarea[i] = 0.f;
  }
  unsigned long long vb = __ballot(valid);
  if (threadIdx.x == 0) vmask[blockIdx.x] = vb;
}

// ---------------- NMS stage 4: pairwise IoU suppression bitmask ----------------
__global__ __launch_bounds__(64) void nms_mask(
    const float* __restrict__ sbox, const float* __restrict__ sarea,
    unsigned long long* __restrict__ mask) {
  const int cb = blockIdx.x, rb = blockIdx.y;
  const int t = threadIdx.x;
  const int r = rb * 64 + t;
  if (cb < rb) { mask[(size_t)r * NW + cb] = 0ULL; return; }
  __shared__ float cx1[64], cy1[64], cx2[64], cy2[64], car[64];
  int j = cb * 64 + t;
  cx1[t] = sbox[j * 4 + 0]; cy1[t] = sbox[j * 4 + 1];
  cx2[t] = sbox[j * 4 + 2]; cy2[t] = sbox[j * 4 + 3];
  car[t] = sarea[j];
  __syncthreads();
  float rx1 = sbox[r * 4 + 0], ry1 = sbox[r * 4 + 1];
  float rx2 = sbox[r * 4 + 2], ry2 = sbox[r * 4 + 3];
  float rar = sarea[r];
  unsigned long long m = 0;
  int c0 = (cb == rb) ? (t + 1) : 0;
  for (int c = c0; c < 64; ++c) {
    float iw = fmaxf(fminf(rx2, cx2[c]) - fmaxf(rx1, cx1[c]), 0.f);
    float ih = fmaxf(fminf(ry2, cy2[c]) - fmaxf(ry1, cy1[c]), 0.f);
    float inter = iw * ih;
    float iou = inter / fmaxf(rar + car[c] - inter, 1e-12f);
    if (iou > 0.7f) m |= (1ULL << c);
  }
  mask[(size_t)r * NW + cb] = m;
}

// ---------------- NMS stage 5: serial bitmask scan, one wave ----------------
__global__ __launch_bounds__(64) void nms_scan(
    const unsigned long long* __restrict__ vmask,
    const unsigned long long* __restrict__ mask,
    const float* __restrict__ sbox, float* __restrict__ dout) {
  float* props  = dout;
  float* validf = dout + 4000;
  const int l = threadIdx.x;
  unsigned long long rem0 = 0, rem1 = 0;
  unsigned long long v0 = vmask[l];
  unsigned long long v1 = (l < 24) ? vmask[64 + l] : 0ULL;
  int kept = 0;
  for (int w = 0; w < NW; ++w) {
    int owner = (w < 64) ? w : (w - 64);
    for (;;) {
      unsigned long long myc = (w < 64) ? (v0 & ~rem0) : (v1 & ~rem1);
      unsigned long long cand = shfl_u64(myc, owner);
      if (!cand) break;
      int b = __ffsll((unsigned long long)cand) - 1;
      int i = w * 64 + b;
      if (l < 4) props[kept * 4 + l] = sbox[(size_t)i * 4 + l];
      if (l == 0) validf[kept] = 1.0f;
      kept++;
      if (kept == 1000) { w = NW; break; }
      unsigned long long m0 = mask[(size_t)i * NW + l];
      unsigned long long m1 = (l < 24) ? mask[(size_t)i * NW + 64 + l] : 0ULL;
      rem0 |= m0; rem1 |= m1;
      if (w < 64) { if (l == w) rem0 |= (1ULL << b); }
      else        { if (l == w - 64) rem1 |= (1ULL << b); }
    }
  }
  for (int z = kept * 4 + l; z < 4000; z += 64) props[z] = 0.f;
  for (int z = kept + l; z < 1000; z += 64) validf[z] = 0.f;
}

// ---------------- ROI max-pool -> bf16 feats [1024][25088] ----------------
__global__ __launch_bounds__(256) void roipool_kernel(
    const float* __restrict__ feat, const float* __restrict__ dout,
    const int* __restrict__ Wp, unsigned short* __restrict__ feats) {
  const int r = blockIdx.x;
  const int t = threadIdx.x;
  const float* props  = dout;
  const float* validf = dout + 4000;
  unsigned short* outr = feats + (size_t)r * 25088;
  bool dead = (r >= 1000) || (validf[r] == 0.0f);
  if (dead) {
    for (int i = t; i < 25088; i += 256) outr[i] = 0;
    return;
  }
  const float scale = 1.0f / (float)((*Wp) / 25);
  __shared__ int hs_[7], he_[7], ws_[7], we_[7];
  if (t < 7) {
    float fx1 = props[r * 4 + 0], fy1 = props[r * 4 + 1];
    float fx2 = props[r * 4 + 2], fy2 = props[r * 4 + 3];
    int x1 = (int)rintf(fx1 * scale), y1 = (int)rintf(fy1 * scale);
    int x2 = (int)rintf(fx2 * scale), y2 = (int)rintf(fy2 * scale);
    float roiw = (float)max(x2 - x1 + 1, 1);
    float roih = (float)max(y2 - y1 + 1, 1);
    float bw = roiw / 7.0f, bh = roih / 7.0f;
    float jf = (float)t;
    int w0 = (int)floorf(jf * bw) + x1;
    int w1 = (int)ceilf((jf + 1.f) * bw) + x1;
    int h0 = (int)floorf(jf * bh) + y1;
    int h1 = (int)ceilf((jf + 1.f) * bh) + y1;
    ws_[t] = min(max(w0, 0), 25); we_[t] = min(max(w1, 0), 25);
    hs_[t] = min(max(h0, 0), 25); he_[t] = min(max(h1, 0), 25);
  }
  __syncthreads();
  for (int idx = t; idx < 25088; idx += 256) {
    int c = idx / 49;
    int ij = idx % 49;
    int i = ij / 7, j = ij % 7;
    int h0 = hs_[i], h1 = min(he_[i], h0 + 6);
    int w0 = ws_[j], w1 = min(we_[j], w0 + 6);
    float m = NEGINF;
    const float* fp = feat + (size_t)c * 625;
    for (int y = h0; y < h1; y++)
      for (int x = w0; x < w1; x++)
        m = fmaxf(m, fp[y * 25 + x]);
    outr[idx] = (h0 < h1 && w0 < w1) ? f2bf(m) : 0;
  }
}

// ---------------- bf16 MFMA GEMM (m97 structure) ----------------
__global__ __launch_bounds__(256) void gemm_bt_bf16(
    const unsigned short* __restrict__ A, int lda,
    const unsigned short* __restrict__ B, int ldb,
    const float* __restrict__ bias, float* __restrict__ C, int ldc,
    int K, int beta) {
  __shared__ unsigned short As[128 * 32];
  __shared__ unsigned short Bs[128 * 32];
  const int t = threadIdx.x;
  const int lane = t & 63;
  const int wv = t >> 6;
  const int wr = wv >> 1, wc = wv & 1;
  const int quad = lane >> 4, l16 = lane & 15;
  const int m0 = blockIdx.x * 128, n0 = blockIdx.y * 128;
  floatx4 acc[4][4];
#pragma unroll
  for (int mi = 0; mi < 4; mi++)
#pragma unroll
    for (int ni = 0; ni < 4; ni++) acc[mi][ni] = (floatx4){0.f, 0.f, 0.f, 0.f};
  const int srow = t >> 2;
  const int scol = (t & 3) * 8;
  const unsigned short* Ag0 = A + (size_t)(m0 + srow) * lda + scol;
  const unsigned short* Ag1 = A + (size_t)(m0 + 64 + srow) * lda + scol;
  const unsigned short* Bg0 = B + (size_t)(n0 + srow) * ldb + scol;
  const unsigned short* Bg1 = B + (size_t)(n0 + 64 + srow) * ldb + scol;
  unsigned short* la0 = As + t * 8;
  unsigned short* la1 = As + 2048 + t * 8;
  unsigned short* lb0 = Bs + t * 8;
  unsigned short* lb1 = Bs + 2048 + t * 8;
  for (int kt = 0; kt < K; kt += 32) {
    __syncthreads();
    gload16(Ag0 + kt, la0);
    gload16(Ag1 + kt, la1);
    gload16(Bg0 + kt, lb0);
    gload16(Bg1 + kt, lb1);
    __syncthreads();
    short8 af[4], bfr[4];
#pragma unroll
    for (int mi = 0; mi < 4; mi++)
      af[mi] = *(const short8*)(As + (wr * 64 + mi * 16 + l16) * 32 + quad * 8);
#pragma unroll
    for (int ni = 0; ni < 4; ni++)
      bfr[ni] = *(const short8*)(Bs + (wc * 64 + ni * 16 + l16) * 32 + quad * 8);
#pragma unroll
    for (int mi = 0; mi < 4; mi++)
#pragma unroll
      for (int ni = 0; ni < 4; ni++)
        acc[mi][ni] = __builtin_amdgcn_mfma_f32_16x16x32_bf16(af[mi], bfr[ni], acc[mi][ni], 0, 0, 0);
  }
#pragma unroll
  for (int mi = 0; mi < 4; mi++) {
#pragma unroll
    for (int ni = 0; ni < 4; ni++) {
      int gn = n0 + wc * 64 + ni * 16 + l16;
      float bv = bias ? bias[gn] : 0.f;
#pragma unroll
      for (int r = 0; r < 4; r++) {
        int gm = m0 + wr * 64 + mi * 16 + quad * 4 + r;
        size_t o = (size_t)gm * ldc + gn;
        float v = acc[mi][ni][r] + bv;
        C[o] = beta ? (C[o] + v) : v;
      }
    }
  }
}

// ---------------- weight / activation conversion kernels ----------------
__global__ __launch_bounds__(256) void cvt_fc1_chunk(
    const float* __restrict__ w, unsigned short* __restrict__ o, int koff) {
  int idx = blockIdx.x * 256 + threadIdx.x;
  int e = idx * 4;
  if (e >= 4096 * 6272) return;
  int n = e / 6272, k = e - n * 6272;
  float4 v = *(const float4*)(w + (size_t)n * 25088 + koff + k);
  ushort4 r = make_ushort4(f2bf(v.x), f2bf(v.y), f2bf(v.z), f2bf(v.w));
  *(ushort4*)(o + e) = r;
}

__global__ __launch_bounds__(256) void cvt_f32_bf16(
    const float* __restrict__ in, unsigned short* __restrict__ out, int n4) {
  int idx = blockIdx.x * 256 + threadIdx.x;
  if (idx >= n4) return;
  float4 v = *(const float4*)(in + (size_t)idx * 4);
  ushort4 r = make_ushort4(f2bf(v.x), f2bf(v.y), f2bf(v.z), f2bf(v.w));
  *(ushort4*)(out + (size_t)idx * 4) = r;
}

__global__ __launch_bounds__(256) void cvt_h1(
    const float* __restrict__ h1, const float* __restrict__ b,
    unsigned short* __restrict__ o) {
  int idx = blockIdx.x * 256 + threadIdx.x;
  int e = idx * 4;
  if (e >= 1024 * 4096) return;
  int col = e & 4095;
  float4 v = *(const float4*)(h1 + e);
  float4 bb = *(const float4*)(b + col);
  ushort4 r = make_ushort4(f2bf(v.x + bb.x), f2bf(v.y + bb.y),
                           f2bf(v.z + bb.z), f2bf(v.w + bb.w));
  *(ushort4*)(o + e) = r;
}

// ---------------- final fc: logits (21) + deltas (4), f32 ----------------
__global__ __launch_bounds__(256) void final_fc(
    const float* __restrict__ h2, const float* __restrict__ cw,
    const float* __restrict__ cb, const float* __restrict__ bw,
    const float* __restrict__ bb, float* __restrict__ logits,
    float* __restrict__ deltas) {
  int r = blockIdx.x;
  const float* x = h2 + (size_t)r * 4096;
  int lane = threadIdx.x & 63, w = threadIdx.x >> 6;
  for (int o = w; o < 25; o += 4) {
    const float* wt = (o < 21) ? (cw + (size_t)o * 4096) : (bw + (size_t)(o - 21) * 4096);
    float s = 0.f;
    for (int k = lane; k < 4096; k += 64) s = fmaf(x[k], wt[k], s);
#pragma unroll
    for (int off = 32; off >= 1; off >>= 1) s += __shfl_xor(s, off);
    if (lane == 0) {
      if (o < 21) logits[r * 21 + o] = s + cb[o];
      else        deltas[r * 4 + (o - 21)] = s + bb[o - 21];
    }
  }
}

extern "C" void kernel_launch(void* const* d_in, const int* in_sizes, int n_in,
                              void* d_out, int out_size, void* d_ws, size_t ws_size,
                              hipStream_t stream) {
  const float* features    = (const float*)d_in[0];
  const float* conv_w      = (const float*)d_in[1];
  const float* conv_b      = (const float*)d_in[2];
  const float* cls_w       = (const float*)d_in[3];
  const float* cls_b       = (const float*)d_in[4];
  const float* reg_w       = (const float*)d_in[5];
  const float* reg_b       = (const float*)d_in[6];
  const float* fc1_w       = (const float*)d_in[7];
  const float* fc1_b       = (const float*)d_in[8];
  const float* fc2_w       = (const float*)d_in[9];
  const float* fc2_b       = (const float*)d_in[10];
  const float* cls_score_w = (const float*)d_in[11];
  const float* cls_score_b = (const float*)d_in[12];
  const float* bbox_w      = (const float*)d_in[13];
  const float* bbox_b      = (const float*)d_in[14];
  const int*   Hp          = (const int*)d_in[15];
  const int*   Wp          = (const int*)d_in[16];
  float* out = (float*)d_out;

  // ---- workspace layout (bytes), peak = 121.1 MB ----
  char* w8 = (char*)d_ws;
  float* xt     = (float*)w8;                    // 1,280,000
  float* clsreg = xt + 320000;                   //   135,000
  float* boxes  = clsreg + 33750;                //    90,000
  float* areas  = boxes + 22500;                 //    22,500
  float* scores = areas + 5625;                  //    22,500  -> small end @1,550,000
  unsigned short* feats = (unsigned short*)(w8 + 1550000);    // 1024*25088*2 = 51,380,224
  float* h1f            = (float*)(w8 + 52930224);            // 1024*4096*4  = 16,777,216
  unsigned short* wchunk = (unsigned short*)(w8 + 69707440);  // 4096*6272*2  = 51,380,224 -> end 121,087,664
  // overlays (regions dead by the time they're used):
  unsigned short* fc2wb = wchunk;                              // 33,554,432 (after fc1 done)
  unsigned short* h1b   = (unsigned short*)(w8 + 69707440 + 33554432); // 8,388,608
  float* h2             = (float*)feats;                       // 16,777,216 (feats dead after fc1)
  // conv scratch overlays the feats region (dead until roipool writes it):
  float* wt_buf = (float*)(w8 + 1550000);                      // 512*4608*4 = 9,437,184
  // NMS scratch also overlays feats region (conv scratch dead by NMS time):
  char* nbase = w8 + 1550000;
  unsigned long long* keys  = (unsigned long long*)nbase;            //    65,536
  float* sbox               = (float*)(nbase + 65536);               //    90,112
  float* sarea              = (float*)(nbase + 155648);              //    22,528
  unsigned long long* vmask = (unsigned long long*)(nbase + 178176); //       704
  unsigned long long* mask  = (unsigned long long*)(nbase + 178880); // 3,965,056 -> end 4,143,936 (< 51 MB)

  // conv3x3: weight transpose + bit-identical high-occupancy conv
  wtrans_kernel<<<dim3(9216), 256, 0, stream>>>(conv_w, wt_buf);
  conv3x3_o2<<<dim3(256, 5), 128, 0, stream>>>(features, wt_buf, conv_b, xt);

  conv1x1_kernel<<<dim3(157), 256, 0, stream>>>(xt, cls_w, cls_b, reg_w, reg_b, clsreg);
  decode_kernel<<<dim3(23), 256, 0, stream>>>(clsreg, Hp, Wp, boxes, areas, scores);

  // ---- NMS: sort + pairwise mask + one-wave bitmask scan (== greedy NMS) ----
  nms_pack<<<dim3(SORTN / 256), 256, 0, stream>>>(scores, keys);
  nms_sort<<<dim3(1), 1024, 0, stream>>>(keys);
  nms_unpack<<<dim3(NW), 64, 0, stream>>>(keys, boxes, areas, sbox, sarea, vmask);
  nms_mask<<<dim3(NW, NW), 64, 0, stream>>>(sbox, sarea, mask);
  nms_scan<<<dim3(1), 64, 0, stream>>>(vmask, mask, sbox, out);

  roipool_kernel<<<dim3(1024), 256, 0, stream>>>(features, out, Wp, feats);

  // fc1: (1024,25088)bf16 x (4096,25088)^T in 4 K-chunks of 6272, accumulate f32
  for (int kc = 0; kc < 4; kc++) {
    cvt_fc1_chunk<<<dim3(25088), 256, 0, stream>>>(fc1_w, wchunk, kc * 6272);
    gemm_bt_bf16<<<dim3(8, 32), 256, 0, stream>>>(
        feats + kc * 6272, 25088, wchunk, 6272, nullptr, h1f, 4096, 6272, kc > 0 ? 1 : 0);
  }
  cvt_h1<<<dim3(4096), 256, 0, stream>>>(h1f, fc1_b, h1b);

  // fc2: (1024,4096) x (4096,4096)^T + bias -> h2 f32
  cvt_f32_bf16<<<dim3(16384), 256, 0, stream>>>(fc2_w, fc2wb, 4194304);
  gemm_bt_bf16<<<dim3(8, 32), 256, 0, stream>>>(
      h1b, 4096, fc2wb, 4096, fc2_b, h2, 4096, 4096, 0);

  // logits + deltas
  final_fc<<<dim3(1000), 256, 0, stream>>>(h2, cls_score_w, cls_score_b,
                                           bbox_w, bbox_b, out + 5000, out + 26000);
}